// Round 13
// baseline (194.919 us; speedup 1.0000x reference)
//
#include <hip/hip_runtime.h>
#include <hip/hip_bf16.h>
#include <math.h>

// Sizes (fixed by the problem)
#define BB   16
#define TT   512
#define HH   512
#define VV   4096
#define LL   64
#define SS   129           // 2*L+1
#define JJ   65            // distinct symbols per sample: blank + L labels
#define MM   (BB*TT)       // 8192 GEMM rows

#define LOG2E 1.4426950408889634f
#define LN2   0.6931471805599453f

typedef __bf16 bf16;
typedef __attribute__((ext_vector_type(4))) __bf16 bf16x4;
typedef __attribute__((ext_vector_type(8))) __bf16 bf16x8;
typedef __attribute__((ext_vector_type(4))) float f32x4;

// DPP helpers ---------------------------------------------------------------
template<int CTRL>
__device__ __forceinline__ float dpp_mov(float x) {   // moved value (all lanes valid)
    return __int_as_float(__builtin_amdgcn_update_dpp(
        __float_as_int(x), __float_as_int(x), CTRL, 0xF, 0xF, false));
}
__device__ __forceinline__ float row16_max(float x) {
    x = fmaxf(x, dpp_mov<0x128>(x));  // row_ror:8
    x = fmaxf(x, dpp_mov<0x124>(x));  // row_ror:4
    x = fmaxf(x, dpp_mov<0x122>(x));  // row_ror:2
    x = fmaxf(x, dpp_mov<0x121>(x));  // row_ror:1
    return x;
}
__device__ __forceinline__ float row16_sum(float x) {
    x += dpp_mov<0x128>(x);
    x += dpp_mov<0x124>(x);
    x += dpp_mov<0x122>(x);
    x += dpp_mov<0x121>(x);
    return x;
}
__device__ __forceinline__ float dpp_shr1_zero(float x) {  // wave shift; lane0 -> 0
    int r = __builtin_amdgcn_update_dpp(0, __float_as_int(x),
                                        0x138 /*wave_shr:1*/, 0xF, 0xF, false);
    return __int_as_float(r);
}
template<int CTRL>
__device__ __forceinline__ float dpp_max_t(float m) {
    int r = __builtin_amdgcn_update_dpp(0, __float_as_int(m), CTRL, 0xF, 0xF, false);
    return fmaxf(m, __int_as_float(r));
}

// ---------------------------------------------------------------------------
// Kernel 0: fused prep. Blocks [0,4096): hs f32 -> Abf bf16.
// Blocks [4096,4608): W [K][N] f32 -> Wt [N][K] bf16 (64x64 LDS transpose).
// Block 0 thread 0 also zeroes out[0] (stream-ordered before ctc_tail's atomics).
// ---------------------------------------------------------------------------
__global__ __launch_bounds__(256) void prep(const float* __restrict__ hs,
                                            const float* __restrict__ W,
                                            bf16* __restrict__ Abf,
                                            bf16* __restrict__ Wt,
                                            float* __restrict__ out)
{
    __shared__ float t[64][65];
    const int tid = threadIdx.x;
    int bx = blockIdx.x;
    if (bx == 0 && tid == 0) out[0] = 0.f;
    if (bx < 4096) {
        int idx = bx * 256 + tid;            // one float4 per thread
        float4 v = ((const float4*)hs)[idx];
        bf16x4 o = {(bf16)v.x, (bf16)v.y, (bf16)v.z, (bf16)v.w};
        *(bf16x4*)(Abf + (size_t)idx * 4) = o;
    } else {
        bx -= 4096;
        const int n0 = (bx & 63) * 64;
        const int k0 = (bx >> 6) * 64;
        #pragma unroll
        for (int i = 0; i < 16; ++i) {
            int idx = tid + i * 256;
            int kk = idx >> 6, nn = idx & 63;
            t[kk][nn] = W[(size_t)(k0 + kk) * VV + n0 + nn];
        }
        __syncthreads();
        #pragma unroll
        for (int i = 0; i < 16; ++i) {
            int idx = tid + i * 256;
            int nl = idx >> 6, kk = idx & 63;
            Wt[(size_t)(n0 + nl) * HH + k0 + kk] = (bf16)t[kk][nl];
        }
    }
}

// ---------------------------------------------------------------------------
// Kernel 1: bf16 MFMA GEMM + LSE partials + label-column scatter.
// r13: BK=64 (8 K-steps x 32 MFMA; half the barrier drains of BK=32).
// LDS rows are 8 x 16B slots; swizzle involution slot ^= row&7 on BOTH sides
// (pre-swizzled global source + swizzled ds_read). 8-lane issue groups cover
// all 32 banks exactly once -> conflict-free.
// ---------------------------------------------------------------------------
#define TN 128
#define NT64 (VV / 64)     // 64 column-tiles of width 64

#define GLDS(src, dst) \
    __builtin_amdgcn_global_load_lds((const __attribute__((address_space(1))) void*)(src), \
                                     (__attribute__((address_space(3))) void*)(dst), 16, 0, 0)

__global__ __launch_bounds__(256) void gemm_lse_mfma(
    const bf16* __restrict__ A,    // [M][512] bf16
    const bf16* __restrict__ Bt,   // [N=4096][512] bf16 (W transposed)
    const float* __restrict__ bias,
    const int*  __restrict__ ys,   // [BB][LL]
    float* __restrict__ part,      // [M][NT64][2] (max, sumexp)
    float* __restrict__ glpT)      // [BB][JJ][TT] raw label logits + bias
{
    __shared__ bf16 As[128 * 64];
    __shared__ bf16 Bs[128 * 64];
    const int tid = threadIdx.x;
    const int lane = tid & 63;
    const int wid = tid >> 6;
    const int wm = wid >> 1, wn = wid & 1;
    const int m0 = blockIdx.y * 128, n0 = blockIdx.x * 128;
    const int lq = lane & 15, kg = lane >> 4;

    f32x4 acc[4][4];
    const f32x4 z = {0.f, 0.f, 0.f, 0.f};
    #pragma unroll
    for (int i = 0; i < 4; ++i)
        #pragma unroll
        for (int j = 0; j < 4; ++j) acc[i][j] = z;

    // staging: 1024 16B-chunks per matrix; 4 per thread. chunk c = tid + i*256.
    // row = c>>3, slot = (c&7) ^ (row&7). LDS dst = wave-uniform base (HW adds lane*16).
    const bf16* srcA[4];
    const bf16* srcB[4];
    #pragma unroll
    for (int i = 0; i < 4; ++i) {
        int c = tid + i * 256;
        int row = c >> 3;
        int slot = (c & 7) ^ (row & 7);
        srcA[i] = A  + (size_t)(m0 + row) * HH + slot * 8;
        srcB[i] = Bt + (size_t)(n0 + row) * HH + slot * 8;
    }

    for (int k0 = 0; k0 < HH; k0 += 64) {
        #pragma unroll
        for (int i = 0; i < 4; ++i)
            GLDS(srcA[i] + k0, As + (size_t)(i * 256 + (tid & 192)) * 8);
        #pragma unroll
        for (int i = 0; i < 4; ++i)
            GLDS(srcB[i] + k0, Bs + (size_t)(i * 256 + (tid & 192)) * 8);
        __syncthreads();
        #pragma unroll
        for (int kk = 0; kk < 2; ++kk) {      // K sub-step of 32
            bf16x8 a[4], b[4];
            #pragma unroll
            for (int i = 0; i < 4; ++i) {
                int ar = wm * 64 + i * 16 + lq;
                a[i] = *(const bf16x8*)&As[ar * 64 + (((kg + kk * 4) ^ (ar & 7)) * 8)];
            }
            #pragma unroll
            for (int j = 0; j < 4; ++j) {
                int br = wn * 64 + j * 16 + lq;
                b[j] = *(const bf16x8*)&Bs[br * 64 + (((kg + kk * 4) ^ (br & 7)) * 8)];
            }
            #pragma unroll
            for (int i = 0; i < 4; ++i)
                #pragma unroll
                for (int j = 0; j < 4; ++j)
                    acc[i][j] = __builtin_amdgcn_mfma_f32_16x16x32_bf16(a[i], b[j], acc[i][j], 0, 0, 0);
        }
        __syncthreads();
    }

    // ---- epilogue (a): bias + per-row (this wave's 64-col half) max/sumexp
    const int ct = blockIdx.x * 2 + wn;   // 64-col tile index (race-free)
    float bj[4];
    #pragma unroll
    for (int j = 0; j < 4; ++j) bj[j] = bias[n0 + wn * 64 + j * 16 + lq];
    #pragma unroll
    for (int i = 0; i < 4; ++i) {
        #pragma unroll
        for (int r = 0; r < 4; ++r) {
            float v[4], mx = -3.4e38f;
            #pragma unroll
            for (int j = 0; j < 4; ++j) { v[j] = acc[i][j][r] + bj[j]; mx = fmaxf(mx, v[j]); }
            mx = row16_max(mx);
            float sm = 0.f;
            #pragma unroll
            for (int j = 0; j < 4; ++j) sm += __expf(v[j] - mx);
            sm = row16_sum(sm);
            if (lq == 0) {
                int rowg = m0 + wm * 64 + i * 16 + kg * 4 + r;
                size_t o = ((size_t)rowg * NT64 + ct) * 2;
                part[o] = mx; part[o + 1] = sm;
            }
        }
    }

    // ---- epilogue (b): scatter label columns -> glpT[b][j][t] (scalar stores)
    const int bidx = m0 >> 9;               // sample (512 rows per sample)
    const int t0s  = (m0 & 511) + wm * 64;  // base t for this wave
    const int nbase = n0 + wn * 64;
    for (int j = 0; j < JJ; ++j) {
        int c = (j == 0) ? 0 : ys[bidx * LL + j - 1];   // uniform
        int local = c - nbase;
        if (local >= 0 && local < 64) {     // uniform branch (~2 hits/wave)
            int cl = local & 15;
            float bc = bias[c];
            #pragma unroll
            for (int jt = 0; jt < 4; ++jt) {   // static jt: keep acc in regs
                if ((local >> 4) == jt && lq == cl) {
                    #pragma unroll
                    for (int i = 0; i < 4; ++i)
                        #pragma unroll
                        for (int r = 0; r < 4; ++r) {
                            int tt = t0s + i * 16 + kg * 4 + r;
                            glpT[(size_t)(bidx * JJ + j) * TT + tt] = acc[i][jt][r] + bc;
                        }
                }
            }
        }
    }
}

// ---------------------------------------------------------------------------
// Kernel 2: fused tail. One block per sample (16 x 256 threads).
// Wave 0: register DP (linear domain, exact pow2 rescale).
// r13: NO arrays anywhere in wave 0 — emission data lives only in named
// float4 registers; exp2 ratios are named scalars consumed immediately
// (rule #20: indexed arrays were the suspected scratch-spill cause).
// Waves 1-3: per-sample sum of lse from `part`. One barrier; atomicAdd out.
// ---------------------------------------------------------------------------
#define LOADN(pA0,pA1,pA2,pA3,qA0,qA1,qA2,qA3, blk) { \
    int bb_ = (blk); bb_ = bb_ < 32 ? bb_ : 31; \
    const float4* p0_ = (const float4*)(g0 + bb_ * 16); \
    const float4* pB_ = (const float4*)(gB + bb_ * 16); \
    pA0 = p0_[0]; pA1 = p0_[1]; pA2 = p0_[2]; pA3 = p0_[3]; \
    qA0 = pB_[0]; qA1 = pB_[1]; qA2 = pB_[2]; qA3 = pB_[3]; }

#define RESCALE() { \
        float m_ = fmaxf(fmaxf(vA ? A : 0.f, vB ? B : 0.f), vC ? C : 0.f); \
        m_ = dpp_max_t<0x111>(m_); /* row_shr:1 */ \
        m_ = dpp_max_t<0x112>(m_); /* row_shr:2 */ \
        m_ = dpp_max_t<0x114>(m_); /* row_shr:4 */ \
        m_ = dpp_max_t<0x118>(m_); /* row_shr:8 */ \
        m_ = dpp_max_t<0x142>(m_); /* row_bcast:15 */ \
        m_ = dpp_max_t<0x143>(m_); /* row_bcast:31 */ \
        int mb = __builtin_amdgcn_readlane(__float_as_int(m_), 63); \
        int k_ = ((mb >> 23) & 0xFF) - 127; \
        float sc = __int_as_float((127 - k_) << 23); \
        A *= sc; B *= sc; C *= sc; K += k_; \
    }

#define STEP1(rv, t_) { \
        bool upd = ((t_) >= 1) && ((t_) < Tin); \
        float prevB = dpp_shr1_zero(B); \
        float nA = A + prevB; \
        float t1 = A + B; \
        float t2 = skipB ? prevB : 0.f; \
        float nB = (t1 + t2) * (rv); \
        float nC = C + B; \
        A = upd ? nA : A; B = upd ? nB : B; C = upd ? nC : C; }

#define DO4Q(p4, q4, tb) { \
        float r0_ = __builtin_amdgcn_exp2f((q4.x - p4.x) * LOG2E); \
        float r1_ = __builtin_amdgcn_exp2f((q4.y - p4.y) * LOG2E); \
        float r2_ = __builtin_amdgcn_exp2f((q4.z - p4.z) * LOG2E); \
        float r3_ = __builtin_amdgcn_exp2f((q4.w - p4.w) * LOG2E); \
        corr += ((((tb)+0 >= 1) && ((tb)+0 < Tin)) ? p4.x : 0.f) \
              + ((((tb)+1 >= 1) && ((tb)+1 < Tin)) ? p4.y : 0.f) \
              + ((((tb)+2 >= 1) && ((tb)+2 < Tin)) ? p4.z : 0.f) \
              + ((((tb)+3 >= 1) && ((tb)+3 < Tin)) ? p4.w : 0.f); \
        STEP1(r0_, (tb)+0); STEP1(r1_, (tb)+1); \
        STEP1(r2_, (tb)+2); STEP1(r3_, (tb)+3); }

#define DOCHUNK16(P0,P1,P2,P3,Q0,Q1,Q2,Q3, blk) { \
        const int tB_ = (blk) * 16; \
        DO4Q(P0, Q0, tB_ + 0); DO4Q(P1, Q1, tB_ + 4);  RESCALE(); \
        DO4Q(P2, Q2, tB_ + 8); DO4Q(P3, Q3, tB_ + 12); RESCALE(); }

__global__ __launch_bounds__(256) void ctc_tail(
    const float* __restrict__ glpT, const float* __restrict__ part,
    const int* __restrict__ ys, const int* __restrict__ hs_lens,
    const int* __restrict__ ys_lens, float* __restrict__ out)
{
    __shared__ float lsum_sh[4];
    const int b = blockIdx.x;
    const int tid = threadIdx.x;
    const int wave = tid >> 6;
    const int lane = tid & 63;
    const int Tin = hs_lens[b];
    const int Ll  = ys_lens[b];         // 32..64

    float v1 = 0.f, v2 = 0.f, corr = 0.f;
    int K = 0;

    if (wave == 0) {
        // ---------------- wave 0: the DP ----------------
        const int l = lane;
        const float* g0 = glpT + (size_t)(b * JJ) * TT;            // blank row
        const float* gB = glpT + (size_t)(b * JJ + l + 1) * TT;    // label row

        const bool vA = (l <= Ll);
        const bool vB = (l <  Ll);
        const bool vC = (l == 63) && (Ll == 64);

        int cc = ys[b * LL + l];
        bool skipB = false;
        if (l >= 1) { int cp = ys[b * LL + l - 1]; skipB = (cc != 0) && (cc != cp); }

        float raw0_0 = g0[0];
        float d0 = (gB[0] - raw0_0) * LOG2E;
        float A = (l == 0) ? 1.0f : 0.0f;
        float B = (l == 0) ? __builtin_amdgcn_exp2f(d0) : 0.0f;
        float C = 0.0f;
        corr = raw0_0;

        float4 pa0, pa1, pa2, pa3, qa0, qa1, qa2, qa3;
        float4 pb0, pb1, pb2, pb3, qb0, qb1, qb2, qb3;
        LOADN(pa0,pa1,pa2,pa3,qa0,qa1,qa2,qa3, 0);
        LOADN(pb0,pb1,pb2,pb3,qb0,qb1,qb2,qb3, 1);
        for (int blk = 0; blk < 32; blk += 2) {
            DOCHUNK16(pa0,pa1,pa2,pa3,qa0,qa1,qa2,qa3, blk);
            LOADN(pa0,pa1,pa2,pa3,qa0,qa1,qa2,qa3, blk + 2);
            DOCHUNK16(pb0,pb1,pb2,pb3,qb0,qb1,qb2,qb3, blk + 1);
            LOADN(pb0,pb1,pb2,pb3,qb0,qb1,qb2,qb3, blk + 3);
            if (16 * (blk + 2) >= Tin) break;
        }

        v1 = (Ll == 64) ? __shfl(C, 63, 64) : __shfl(A, Ll, 64);  // ah[2Ll]
        v2 = __shfl(B, Ll - 1, 64);                                // ah[2Ll-1]
    } else {
        // ---------------- waves 1-3: sum of lse over t < Tin ----------------
        const int t0 = (wave - 1) * 171;
        const int t1 = (t0 + 171 < TT) ? (t0 + 171) : TT;
        const int grp = lane >> 4, li = lane & 15;
        float lsum = 0.f;
        for (int t = t0 + grp; t < t1; t += 4) {
            const float* p = part + ((size_t)(b * TT + t)) * (NT64 * 2) + li * 8;
            float4 a  = ((const float4*)p)[0];
            float4 c4 = ((const float4*)p)[1];
            float ml = fmaxf(fmaxf(a.x, a.z), fmaxf(c4.x, c4.z));
            float sl = a.y  * __expf(a.x  - ml) + a.w  * __expf(a.z  - ml)
                     + c4.y * __expf(c4.x - ml) + c4.w * __expf(c4.z - ml);
            float wm = row16_max(ml);
            float ss = row16_sum(sl * __expf(ml - wm));
            if (li == 0 && t < Tin) lsum += wm + logf(ss);
        }
        #pragma unroll
        for (int d = 1; d < 64; d <<= 1) lsum += __shfl_xor(lsum, d);
        if (lane == 0) lsum_sh[wave] = lsum;
    }
    __syncthreads();
    if (tid == 0) {
        float lsumT = lsum_sh[1] + lsum_sh[2] + lsum_sh[3];
        float ll2 = __builtin_amdgcn_logf(v1 + v2) + (float)K + (corr - lsumT) * LOG2E;
        atomicAdd(out, (-ll2 * LN2) * (1.0f / (float)BB));
    }
}

// ---------------------------------------------------------------------------
extern "C" void kernel_launch(void* const* d_in, const int* in_sizes, int n_in,
                              void* d_out, int out_size, void* d_ws, size_t ws_size,
                              hipStream_t stream) {
    const float* hs      = (const float*)d_in[0];   // [16,512,512] f32
    const int*   hs_lens = (const int*)  d_in[1];   // [16]
    const int*   ys      = (const int*)  d_in[2];   // [16,64]
    const int*   ys_lens = (const int*)  d_in[3];   // [16]
    const float* W       = (const float*)d_in[4];   // [512,4096] f32
    const float* bias    = (const float*)d_in[5];   // [4096]
    float* out = (float*)d_out;

    float* ws   = (float*)d_ws;
    float* part = ws;                                // M*NT64*2 = 1048576 f
    float* glpT = part + (size_t)MM * NT64 * 2;      // B*J*T = 532480 f
    bf16*  Abf  = (bf16*)(glpT + (size_t)BB * JJ * TT);  // 4194304 bf16
    bf16*  Wt   = Abf + (size_t)MM * HH;             // 2097152 bf16

    prep<<<4608, 256, 0, stream>>>(hs, W, Abf, Wt, out);
    gemm_lse_mfma<<<dim3(VV / TN, MM / 128), 256, 0, stream>>>(Abf, Wt, bias, ys, part, glpT);
    ctc_tail<<<BB, 256, 0, stream>>>(glpT, part, ys, hs_lens, ys_lens, out);
}